// Round 3
// baseline (81.426 us; speedup 1.0000x reference)
//
#include <hip/hip_runtime.h>

// KAN 2x2 convolution, stride 1, summed over C=16 channels.
// x: (8,16,128,128) fp32 -> out: (8,1,127,127) fp32
//
// Round-3 structure (register/shfl, no LDS staging, no inner syncs):
//  - uniform-knot cubic B-spline folded into per-(interval t, position p)
//    cubic coefficient table coef[11][4] (float4 = c0..c3) in LDS (704 B),
//    exact reformulation of Cox-de-Boor for the uniform grid (rounds 1-2).
//  - each thread computes 4 consecutive outputs of one row: two float4 loads
//    (rows y, y+1) per channel + __shfl_down for the 5th column value.
//    Each value is pair-evaluated: (p0,p1) for top-row role, (p2,p3) for
//    bottom-row role -> 2 LDS b128 + ~20 VALU per eval.
//  - CG=2 channels per block -> 1024 blocks (4/CU, 16 waves/CU); partials
//    combined with one atomicAdd per output element (8 writers/address,
//    negligible contention). d_out zeroed via hipMemsetAsync node.

#define IN_F 4
#define N_COEF 8
#define N_INT 11
#define CG 2

__device__ __forceinline__ float silu(float x) {
    return x * __builtin_amdgcn_rcpf(1.0f + __expf(-x));
}

__global__ __launch_bounds__(256) void kan_conv_kernel(
    const float* __restrict__ x,
    const float* __restrict__ base_w,    // (1,4)
    const float* __restrict__ spline_w,  // (1,4,8)
    const float* __restrict__ spline_s,  // (1,4)
    const float* __restrict__ grid,      // (4,12) identical uniform rows
    float* __restrict__ out,
    int B, int C, int H, int W)
{
    const int Ho = H - 1, Wo = W - 1;  // 127,127

    __shared__ float4 coef[N_INT][IN_F];  // [t][p] -> cubic coeffs in u
    __shared__ float  s_misc[6];          // bw0..3, g0, invh

    const int tid = threadIdx.x;
    if (tid < N_INT * IN_F) {
        const int t = tid / IN_F;
        const int p = tid % IN_F;
        // uniform cubic B-spline blending matrix (power basis in u)
        const float M[4][4] = {
            {1.f/6.f, -3.f/6.f,  3.f/6.f, -1.f/6.f},
            {4.f/6.f,  0.f,     -6.f/6.f,  3.f/6.f},
            {1.f/6.f,  3.f/6.f,  3.f/6.f, -3.f/6.f},
            {0.f,      0.f,      0.f,      1.f/6.f}};
        const float scal = spline_s[p];
        float c0 = 0.f, c1 = 0.f, c2 = 0.f, c3 = 0.f;
        #pragma unroll
        for (int m = 0; m < 4; ++m) {
            const int j = t - 3 + m;
            const float w = (j >= 0 && j < N_COEF)
                              ? spline_w[p * N_COEF + j] * scal : 0.f;
            c0 += M[m][0] * w; c1 += M[m][1] * w;
            c2 += M[m][2] * w; c3 += M[m][3] * w;
        }
        coef[t][p] = make_float4(c0, c1, c2, c3);
    }
    if (tid < IN_F) s_misc[tid] = base_w[tid];
    if (tid == 4)   s_misc[4] = grid[0];
    if (tid == 5)   s_misc[5] = 1.0f / (grid[1] - grid[0]);
    __syncthreads();

    const float bw0 = s_misc[0], bw1 = s_misc[1];
    const float bw2 = s_misc[2], bw3 = s_misc[3];
    const float g0 = s_misc[4], invh = s_misc[5];

    // grid: 8 batches x 16 row-tiles x 8 channel-groups = 1024 blocks
    int bid = blockIdx.x;
    const int cg  = bid & 7;  bid >>= 3;
    const int tyi = bid & 15; bid >>= 4;
    const int b   = bid;

    const int g  = tid & 31;      // lane-group: 4 outputs each
    const int r  = tid >> 5;      // row within tile, 0..7
    const int oy = tyi * 8 + r;
    const int ys = (oy < Ho) ? oy : (Ho - 1);  // clamp; garbage rows masked
    const int ox = g * 4;

    float acc0 = 0.f, acc1 = 0.f, acc2 = 0.f, acc3 = 0.f;

    #pragma unroll
    for (int cc = 0; cc < CG; ++cc) {
        const int c = cg * CG + cc;
        const float* __restrict__ xc = x + ((size_t)(b * C + c) * H) * W;

        const float4 r0 = *(const float4*)(xc + (size_t)ys * W + ox);
        const float4 r1 = *(const float4*)(xc + (size_t)(ys + 1) * W + ox);
        const float a4 = __shfl_down(r0.x, 1);  // lane g+1's col 4g+4 (row ys)
        const float b4 = __shfl_down(r1.x, 1);  // garbage only for masked outs

        const float av[5] = {r0.x, r0.y, r0.z, r0.w, a4};
        const float bv[5] = {r1.x, r1.y, r1.z, r1.w, b4};
        float f0[5], f1[5], f2[5], f3[5];

        #pragma unroll
        for (int k = 0; k < 5; ++k) {
            {   // top-row value: window positions p=0 (left), p=1 (right)
                const float v   = av[k];
                const float sil = silu(v);
                const float tf  = (v - g0) * invh;
                const float tfl = floorf(tf);
                const int   ti  = (int)tfl;
                const float u   = tf - tfl;
                const bool  ok  = ((unsigned)ti < (unsigned)N_INT);
                const int   t   = ok ? ti : 0;
                const float4 ca = coef[t][0];
                const float4 cb = coef[t][1];
                float sa = fmaf(u, ca.w, ca.z);
                sa = fmaf(u, sa, ca.y); sa = fmaf(u, sa, ca.x);
                float sb = fmaf(u, cb.w, cb.z);
                sb = fmaf(u, sb, cb.y); sb = fmaf(u, sb, cb.x);
                f0[k] = fmaf(sil, bw0, ok ? sa : 0.f);
                f1[k] = fmaf(sil, bw1, ok ? sb : 0.f);
            }
            {   // bottom-row value: window positions p=2, p=3
                const float v   = bv[k];
                const float sil = silu(v);
                const float tf  = (v - g0) * invh;
                const float tfl = floorf(tf);
                const int   ti  = (int)tfl;
                const float u   = tf - tfl;
                const bool  ok  = ((unsigned)ti < (unsigned)N_INT);
                const int   t   = ok ? ti : 0;
                const float4 ca = coef[t][2];
                const float4 cb = coef[t][3];
                float sa = fmaf(u, ca.w, ca.z);
                sa = fmaf(u, sa, ca.y); sa = fmaf(u, sa, ca.x);
                float sb = fmaf(u, cb.w, cb.z);
                sb = fmaf(u, sb, cb.y); sb = fmaf(u, sb, cb.x);
                f2[k] = fmaf(sil, bw2, ok ? sa : 0.f);
                f3[k] = fmaf(sil, bw3, ok ? sb : 0.f);
            }
        }

        acc0 += f0[0] + f1[1] + f2[0] + f3[1];
        acc1 += f0[1] + f1[2] + f2[1] + f3[2];
        acc2 += f0[2] + f1[3] + f2[2] + f3[3];
        acc3 += f0[3] + f1[4] + f2[3] + f3[4];
    }

    if (oy < Ho) {
        float* orow = out + ((size_t)b * Ho + oy) * Wo + ox;
        atomicAdd(orow + 0, acc0);
        atomicAdd(orow + 1, acc1);
        atomicAdd(orow + 2, acc2);
        if (ox + 3 < Wo) atomicAdd(orow + 3, acc3);
    }
}

extern "C" void kernel_launch(void* const* d_in, const int* in_sizes, int n_in,
                              void* d_out, int out_size, void* d_ws, size_t ws_size,
                              hipStream_t stream) {
    const float* x        = (const float*)d_in[0];
    const float* base_w   = (const float*)d_in[1];
    const float* spline_w = (const float*)d_in[2];
    const float* spline_s = (const float*)d_in[3];
    const float* grid     = (const float*)d_in[4];
    float* out = (float*)d_out;

    const int B = 8, C = 16, H = 128, W = 128;

    hipMemsetAsync(out, 0, (size_t)out_size * sizeof(float), stream);

    // 8 batches x 16 row-tiles x 8 channel-groups = 1024 blocks
    kan_conv_kernel<<<1024, 256, 0, stream>>>(
        x, base_w, spline_w, spline_s, grid, out, B, C, H, W);
}